// Round 11
// baseline (198.137 us; speedup 1.0000x reference)
//
#include <hip/hip_runtime.h>

#define DV 1024
#define HD 64

typedef short v4s __attribute__((ext_vector_type(4)));
typedef short v8s __attribute__((ext_vector_type(8)));
typedef float v4f __attribute__((ext_vector_type(4)));
typedef int   v2i __attribute__((ext_vector_type(2)));

__device__ __forceinline__ short f2bf(float x){
  unsigned u = __float_as_uint(x);
  u += 0x7FFFu + ((u >> 16) & 1u);
  return (short)(u >> 16);
}

// XOR-swizzle for 64-short rows read as b128 (8-lane phases → conflict-free)
__device__ __forceinline__ int swz(int lane){
  return (((lane & 7) ^ (lane >> 3)) << 3);   // in shorts
}

// async global->LDS, 16B per lane; LDS dest is wave-uniform base + lane*16
__device__ __forceinline__ void gload16(const short* g, short* l){
  __builtin_amdgcn_global_load_lds(
      (const __attribute__((address_space(1))) void*)g,
      (__attribute__((address_space(3))) void*)l,
      16, 0, 0);
}

// ---------- f32 -> bf16 convert, 2 tensors in one launch ----------
__global__ __launch_bounds__(256) void cvt2(const float* __restrict__ xa,
                                            const float* __restrict__ xb,
                                            short* __restrict__ ya,
                                            short* __restrict__ yb, int n){
  const float* x = blockIdx.y ? xb : xa;
  short* y = blockIdx.y ? yb : ya;
  int stride = gridDim.x * 256 * 4;
  for (int i = (blockIdx.x * 256 + threadIdx.x) * 4; i < n; i += stride){
    float4 v = *(const float4*)(x + i);
    v4s s; s.x = f2bf(v.x); s.y = f2bf(v.y); s.z = f2bf(v.z); s.w = f2bf(v.w);
    *(v4s*)(y + i) = s;
  }
}

// ---------- W[k][n] f32 -> Wt[n][k] bf16, all 4 weights in one launch ----------
__global__ __launch_bounds__(256) void tcvt4(
    const float* __restrict__ W0, const float* __restrict__ W1,
    const float* __restrict__ W2, const float* __restrict__ W3,
    short* __restrict__ T0, short* __restrict__ T1,
    short* __restrict__ T2, short* __restrict__ T3){
  const float* W; short* Wt;
  switch (blockIdx.z){
    case 0: W = W0; Wt = T0; break;
    case 1: W = W1; Wt = T1; break;
    case 2: W = W2; Wt = T2; break;
    default: W = W3; Wt = T3; break;
  }
  __shared__ short L[64 * 68];
  const int t = threadIdx.x;
  const int k0 = blockIdx.y * 64, n0 = blockIdx.x * 64;
  const int rr = t >> 4, cc = (t & 15) * 4;
  #pragma unroll
  for (int j = 0; j < 4; j++){
    int r = rr + j * 16;
    float4 v = *(const float4*)(W + (size_t)(k0 + r) * DV + n0 + cc);
    v4s s; s.x = f2bf(v.x); s.y = f2bf(v.y); s.z = f2bf(v.z); s.w = f2bf(v.w);
    *(v4s*)&L[r * 68 + cc] = s;
  }
  __syncthreads();
  #pragma unroll
  for (int j = 0; j < 4; j++){
    int n = rr + j * 16;
    v4s s;
    s.x = L[(cc + 0) * 68 + n];
    s.y = L[(cc + 1) * 68 + n];
    s.z = L[(cc + 2) * 68 + n];
    s.w = L[(cc + 3) * 68 + n];
    *(v4s*)(Wt + (size_t)(n0 + n) * DV + k0 + cc) = s;
  }
}

// ---------- fused projections, PAIRED K/V blocks ----------
__global__ __launch_bounds__(256, 2) void projP(
    const short* __restrict__ qb, const short* __restrict__ kvb,
    const short* __restrict__ Wqt, const short* __restrict__ Wkt,
    const short* __restrict__ Wvt,
    const float* __restrict__ bq, const float* __restrict__ bk,
    const float* __restrict__ bv,
    short* __restrict__ Qp, short* __restrict__ Kp, short* __restrict__ VT,
    float qscale)
{
  __shared__ short S[3 * 8192];   // 48 KB
  const int tid = threadIdx.x;
  const int wave = tid >> 6, lane = tid & 63;
  const int quad = lane >> 4, l15 = lane & 15;
  const int wr = (wave >> 1) * 64, wc = (wave & 1) * 64;
  const int srow = lane >> 3;
  const int sw = swz(lane);
  const int K = 1024;
  const int bid = blockIdx.x;
  const v4f vzero = {0.f, 0.f, 0.f, 0.f};

  if (bid < 256){
    // ---------------- Qp single tile ----------------
    const int m0 = (bid & 31) * 128, n0 = (bid >> 5) * 128;
    short* As = S;
    short* Bs = S + 8192;
    const short* pa[4]; const short* pb[4];
    #pragma unroll
    for (int ii = 0; ii < 4; ii++){
      int i = wave * 4 + ii;
      pa[ii] = qb  + (size_t)(m0 + i * 8 + srow) * K + sw;
      pb[ii] = Wqt + (size_t)(n0 + i * 8 + srow) * K + sw;
    }
    v4f acc[4][4];
    #pragma unroll
    for (int i = 0; i < 4; i++)
      #pragma unroll
      for (int j = 0; j < 4; j++)
        acc[i][j] = vzero;

    for (int kt = 0; kt < K; kt += 64){
      __syncthreads();
      #pragma unroll
      for (int ii = 0; ii < 4; ii++){
        gload16(pa[ii] + kt, &As[(wave * 4 + ii) * 512]);
        gload16(pb[ii] + kt, &Bs[(wave * 4 + ii) * 512]);
      }
      __syncthreads();
      #pragma unroll
      for (int ks = 0; ks < 2; ks++){
        v8s a[4], b[4];
        #pragma unroll
        for (int mt = 0; mt < 4; mt++)
          a[mt] = *(const v8s*)&As[(wr + mt * 16 + l15) * 64 + (((ks * 4 + quad) ^ (l15 & 7)) << 3)];
        #pragma unroll
        for (int nt = 0; nt < 4; nt++)
          b[nt] = *(const v8s*)&Bs[(wc + nt * 16 + l15) * 64 + (((ks * 4 + quad) ^ (l15 & 7)) << 3)];
        #pragma unroll
        for (int mt = 0; mt < 4; mt++)
          #pragma unroll
          for (int nt = 0; nt < 4; nt++)
            acc[mt][nt] = __builtin_amdgcn_mfma_f32_16x16x32_bf16(a[mt], b[nt], acc[mt][nt], 0, 0, 0);
      }
    }
    #pragma unroll
    for (int mt = 0; mt < 4; mt++){
      #pragma unroll
      for (int nt = 0; nt < 4; nt++){
        int row = m0 + wr + mt * 16 + quad * 4;
        int col = n0 + wc + nt * 16 + l15;
        float bcol = bq[col];
        #pragma unroll
        for (int r = 0; r < 4; r++)
          Qp[(size_t)(row + r) * 1024 + col] = f2bf((acc[mt][nt][r] + bcol) * qscale);
      }
    }
  } else {
    // ---------------- paired Kp / VT tiles ----------------
    const int l = bid - 256;
    const int m0 = (l & 31) * 128;        // kv-row tile (32)
    const int j0 = (l >> 5) * 128;        // Kp col-tile == VT row-tile (8)
    short* kvS = S;
    short* wkS = S + 8192;
    short* wvS = S + 16384;
    const short* pkv[4]; const short* pwk[4]; const short* pwv[4];
    #pragma unroll
    for (int ii = 0; ii < 4; ii++){
      int i = wave * 4 + ii;
      pkv[ii] = kvb + (size_t)(m0 + i * 8 + srow) * K + sw;
      pwk[ii] = Wkt + (size_t)(j0 + i * 8 + srow) * K + sw;
      pwv[ii] = Wvt + (size_t)(j0 + i * 8 + srow) * K + sw;
    }
    v4f acc1[4][4], acc2[4][4];
    #pragma unroll
    for (int i = 0; i < 4; i++)
      #pragma unroll
      for (int j = 0; j < 4; j++){
        acc1[i][j] = vzero; acc2[i][j] = vzero;
      }

    for (int kt = 0; kt < K; kt += 64){
      __syncthreads();
      #pragma unroll
      for (int ii = 0; ii < 4; ii++){
        gload16(pkv[ii] + kt, &kvS[(wave * 4 + ii) * 512]);
        gload16(pwk[ii] + kt, &wkS[(wave * 4 + ii) * 512]);
        gload16(pwv[ii] + kt, &wvS[(wave * 4 + ii) * 512]);
      }
      __syncthreads();
      #pragma unroll
      for (int ks = 0; ks < 2; ks++){
        const int off = ((ks * 4 + quad) ^ (l15 & 7)) << 3;
        v8s a1[4], b1[4], a2[4], b2[4];
        #pragma unroll
        for (int mt = 0; mt < 4; mt++){
          a1[mt] = *(const v8s*)&kvS[(wr + mt * 16 + l15) * 64 + off];
          a2[mt] = *(const v8s*)&wvS[(wr + mt * 16 + l15) * 64 + off];
        }
        #pragma unroll
        for (int nt = 0; nt < 4; nt++){
          b1[nt] = *(const v8s*)&wkS[(wc + nt * 16 + l15) * 64 + off];
          b2[nt] = *(const v8s*)&kvS[(wc + nt * 16 + l15) * 64 + off];
        }
        #pragma unroll
        for (int mt = 0; mt < 4; mt++)
          #pragma unroll
          for (int nt = 0; nt < 4; nt++){
            acc1[mt][nt] = __builtin_amdgcn_mfma_f32_16x16x32_bf16(a1[mt], b1[nt], acc1[mt][nt], 0, 0, 0);
            acc2[mt][nt] = __builtin_amdgcn_mfma_f32_16x16x32_bf16(a2[mt], b2[nt], acc2[mt][nt], 0, 0, 0);
          }
      }
    }
    // Kp epilogue: row = kv-m, col = j0-dim, bias per col
    #pragma unroll
    for (int mt = 0; mt < 4; mt++){
      #pragma unroll
      for (int nt = 0; nt < 4; nt++){
        int row = m0 + wr + mt * 16 + quad * 4;
        int col = j0 + wc + nt * 16 + l15;
        float bcol = bk[col];
        #pragma unroll
        for (int r = 0; r < 4; r++)
          Kp[(size_t)(row + r) * 1024 + col] = f2bf(acc1[mt][nt][r] + bcol);
      }
    }
    // VT epilogue: row = d (j0), col = kv-m, bias per row
    #pragma unroll
    for (int mt = 0; mt < 4; mt++){
      #pragma unroll
      for (int nt = 0; nt < 4; nt++){
        int row = j0 + wr + mt * 16 + quad * 4;
        int col = m0 + wc + nt * 16 + l15;
        #pragma unroll
        for (int r = 0; r < 4; r++)
          VT[(size_t)(row + r) * 4096 + col] = f2bf(acc2[mt][nt][r] + bv[row + r]);
      }
    }
  }
}

// ---------- final GEMM: 128x64 tiles, register-prefetch ----------
__global__ __launch_bounds__(256, 2) void gemm_f32(
    const short* __restrict__ A, const short* __restrict__ Bt,
    const float* __restrict__ bias, float* __restrict__ C)
{
  __shared__ short As[128 * 64];
  __shared__ short Bs[64 * 64];
  const int tid = threadIdx.x;
  const int wave = tid >> 6, lane = tid & 63;
  const int quad = lane >> 4, l15 = lane & 15;
  const int bid = blockIdx.x;
  const int m0 = (bid & 31) * 128, n0 = (bid >> 5) * 64;
  const int wr = (wave >> 1) * 64, wc = (wave & 1) * 32;
  const int srow = lane >> 3;
  const int sw = swz(lane);
  const int K = 1024;
  const v4f vzero = {0.f, 0.f, 0.f, 0.f};

  const short* pa[4]; const short* pb[2];
  #pragma unroll
  for (int ii = 0; ii < 4; ii++)
    pa[ii] = A + (size_t)(m0 + (wave * 4 + ii) * 8 + srow) * K + sw;
  #pragma unroll
  for (int ii = 0; ii < 2; ii++)
    pb[ii] = Bt + (size_t)(n0 + (wave * 2 + ii) * 8 + srow) * K + sw;

  v8s ra[4], rb[2];
  #pragma unroll
  for (int ii = 0; ii < 4; ii++) ra[ii] = *(const v8s*)(pa[ii]);
  #pragma unroll
  for (int ii = 0; ii < 2; ii++) rb[ii] = *(const v8s*)(pb[ii]);

  v4f acc[4][2];
  #pragma unroll
  for (int i = 0; i < 4; i++){ acc[i][0] = vzero; acc[i][1] = vzero; }

  for (int kt = 0; kt < K; kt += 64){
    __syncthreads();
    #pragma unroll
    for (int ii = 0; ii < 4; ii++)
      *(v8s*)&As[(wave * 4 + ii) * 512 + lane * 8] = ra[ii];
    #pragma unroll
    for (int ii = 0; ii < 2; ii++)
      *(v8s*)&Bs[(wave * 2 + ii) * 512 + lane * 8] = rb[ii];
    __syncthreads();
    if (kt + 64 < K){
      #pragma unroll
      for (int ii = 0; ii < 4; ii++) ra[ii] = *(const v8s*)(pa[ii] + kt + 64);
      #pragma unroll
      for (int ii = 0; ii < 2; ii++) rb[ii] = *(const v8s*)(pb[ii] + kt + 64);
    }
    #pragma unroll
    for (int ks = 0; ks < 2; ks++){
      v8s a[4], b[2];
      #pragma unroll
      for (int mt = 0; mt < 4; mt++)
        a[mt] = *(const v8s*)&As[(wr + mt * 16 + l15) * 64 + (((ks * 4 + quad) ^ (l15 & 7)) << 3)];
      #pragma unroll
      for (int nt = 0; nt < 2; nt++)
        b[nt] = *(const v8s*)&Bs[(wc + nt * 16 + l15) * 64 + (((ks * 4 + quad) ^ (l15 & 7)) << 3)];
      #pragma unroll
      for (int mt = 0; mt < 4; mt++)
        #pragma unroll
        for (int nt = 0; nt < 2; nt++)
          acc[mt][nt] = __builtin_amdgcn_mfma_f32_16x16x32_bf16(a[mt], b[nt], acc[mt][nt], 0, 0, 0);
    }
  }

  #pragma unroll
  for (int mt = 0; mt < 4; mt++){
    #pragma unroll
    for (int nt = 0; nt < 2; nt++){
      int row = m0 + wr + mt * 16 + quad * 4;
      int col = n0 + wc + nt * 16 + l15;
      float bcol = bias[col];
      #pragma unroll
      for (int r = 0; r < 4; r++)
        C[(size_t)(row + r) * 1024 + col] = acc[mt][nt][r] + bcol;
    }
  }
}

// ---------- flash attention v10: round-9 proven layout (x32 PV, P via
// XOR-64 per-wave LDS tile, V stride 72) + T5 setprio around MFMA clusters
// (2 blocks/CU at different phases -> scheduler can favor the MFMA wave). ----------
__global__ __launch_bounds__(256, 3) void attn(
    const short* __restrict__ Qp, const short* __restrict__ Kp,
    const short* __restrict__ Vt, short* __restrict__ Y)
{
  __shared__ short Ks[64 * 64];
  __shared__ short Vs[64 * 72];
  __shared__ short Ps[4 * 2048];   // per-wave P tiles: [wave][qt][q=16][kv=64 swz]
  const int tid = threadIdx.x;
  const int wave = tid >> 6, lane = tid & 63;
  const int quad = lane >> 4, l15 = lane & 15;
  const int gid = blockIdx.x;
  const int qi = gid >> 5, bh = gid & 31;   // gid%8 == h%8 -> (b,h) pinned to XCD
  const int h = bh & 15, b = bh >> 4;
  const int n0 = qi * 128;
  const int srow = lane >> 3;
  const int c8 = (lane & 7) * 8;
  const int sw = swz(lane);
  const size_t rowbase = (size_t)b * 2048;
  const v4f vzero = {0.f, 0.f, 0.f, 0.f};
  const int l7 = l15 & 7;
  short* Pw = Ps + wave * 2048;

  // ones-row A fragment for 16x16x32: A[row][k]=(row==0); row=l15, k=quad*8+j
  const short oo = (l15 == 0) ? (short)0x3F80 : (short)0;
  const v8s aones8 = {oo, oo, oo, oo, oo, oo, oo, oo};

  v8s qf[2][2];
  #pragma unroll
  for (int qt = 0; qt < 2; qt++){
    const short* qrow = Qp + (rowbase + n0 + wave * 32 + qt * 16 + l15) * DV + h * HD + quad * 8;
    qf[qt][0] = *(const v8s*)(qrow);
    qf[qt][1] = *(const v8s*)(qrow + 32);
  }

  const short* pk[2]; const short* pv[2];
  #pragma unroll
  for (int ii = 0; ii < 2; ii++){
    int i = wave * 2 + ii;
    pk[ii] = Kp + (rowbase + i * 8 + srow) * DV + h * HD + sw;
    pv[ii] = Vt + (size_t)(h * HD + i * 8 + srow) * 4096 + rowbase + c8;
  }
  v8s rk[2], rv[2];
  #pragma unroll
  for (int ii = 0; ii < 2; ii++){ rk[ii] = *(const v8s*)(pk[ii]); rv[ii] = *(const v8s*)(pv[ii]); }

  v4f o[4][2];
  #pragma unroll
  for (int dt = 0; dt < 4; dt++){ o[dt][0] = vzero; o[dt][1] = vzero; }
  v4f lacc[2];
  lacc[0] = vzero; lacc[1] = vzero;

  for (int kt = 0; kt < 32; kt++){
    __syncthreads();
    #pragma unroll
    for (int ii = 0; ii < 2; ii++){
      int i = wave * 2 + ii;
      *(v8s*)&Ks[i * 512 + lane * 8] = rk[ii];
      *(v8s*)&Vs[(i * 8 + srow) * 72 + c8] = rv[ii];
    }
    __syncthreads();
    if (kt < 31){
      #pragma unroll
      for (int ii = 0; ii < 2; ii++){
        rk[ii] = *(const v8s*)(pk[ii] + (size_t)(kt + 1) * 64 * DV);
        rv[ii] = *(const v8s*)(pv[ii] + (kt + 1) * 64);
      }
    }

    // S^T = K * Q^T via 16x16x32: s[qt][kvt] reg r -> (kv = kvt*16+quad*4+r, q = l15)
    v4f s[2][4];
    #pragma unroll
    for (int qt = 0; qt < 2; qt++)
      #pragma unroll
      for (int kvt = 0; kvt < 4; kvt++) s[qt][kvt] = vzero;
    __builtin_amdgcn_s_setprio(1);
    #pragma unroll
    for (int ks = 0; ks < 2; ks++){
      v8s a[4];
      #pragma unroll
      for (int kvt = 0; kvt < 4; kvt++)
        a[kvt] = *(const v8s*)&Ks[(kvt * 16 + l15) * 64 + (((ks * 4 + quad) ^ l7) << 3)];
      #pragma unroll
      for (int kvt = 0; kvt < 4; kvt++)
        #pragma unroll
        for (int qt = 0; qt < 2; qt++)
          s[qt][kvt] = __builtin_amdgcn_mfma_f32_16x16x32_bf16(a[kvt], qf[qt][ks], s[qt][kvt], 0, 0, 0);
    }
    __builtin_amdgcn_s_setprio(0);

    // p = exp2(s); pack to bf16 and write into per-wave P tile (swizzled):
    // logical layout P[q=l15][kv], group g=kv>>3 stored at (g^l7)*8.
    #pragma unroll
    for (int qt = 0; qt < 2; qt++)
      #pragma unroll
      for (int kvt = 0; kvt < 4; kvt++){
        float p0 = __builtin_amdgcn_exp2f(s[qt][kvt][0]);
        float p1 = __builtin_amdgcn_exp2f(s[qt][kvt][1]);
        float p2 = __builtin_amdgcn_exp2f(s[qt][kvt][2]);
        float p3 = __builtin_amdgcn_exp2f(s[qt][kvt][3]);
        unsigned u0 = __float_as_uint(p0) + 0x8000u;
        unsigned u1 = __float_as_uint(p1) + 0x8000u;
        unsigned u2 = __float_as_uint(p2) + 0x8000u;
        unsigned u3 = __float_as_uint(p3) + 0x8000u;
        v2i pi;
        pi.x = (int)__builtin_amdgcn_perm(u1, u0, 0x07060302u);
        pi.y = (int)__builtin_amdgcn_perm(u3, u2, 0x07060302u);
        // kv = kvt*16 + quad*4 + r -> group g = kvt*2 + (quad>>1), sub = (quad&1)*4
        *(v4s*)&Pw[qt * 1024 + l15 * 64 +
                   ((((kvt << 1) | (quad >> 1)) ^ l7) << 3) + ((quad & 1) << 2)]
            = __builtin_bit_cast(v4s, pi);
      }

    // O^T += V^T * P^T on x32 shape: A = V^T (k=kv=blk*32+quad*8+j),
    // B = P (col=q=l15, same k); denominator via ones-row A.
    __builtin_amdgcn_s_setprio(1);
    #pragma unroll
    for (int blk = 0; blk < 2; blk++){
      v8s av[4], pb[2];
      #pragma unroll
      for (int qt = 0; qt < 2; qt++)
        pb[qt] = *(const v8s*)&Pw[qt * 1024 + l15 * 64 + ((((blk << 2) | quad) ^ l7) << 3)];
      #pragma unroll
      for (int dt = 0; dt < 4; dt++)
        av[dt] = *(const v8s*)&Vs[(dt * 16 + l15) * 72 + blk * 32 + quad * 8];
      #pragma unroll
      for (int dt = 0; dt < 4; dt++)
        #pragma unroll
        for (int qt = 0; qt < 2; qt++)
          o[dt][qt] = __builtin_amdgcn_mfma_f32_16x16x32_bf16(av[dt], pb[qt], o[dt][qt], 0, 0, 0);
      #pragma unroll
      for (int qt = 0; qt < 2; qt++)
        lacc[qt] = __builtin_amdgcn_mfma_f32_16x16x32_bf16(aones8, pb[qt], lacc[qt], 0, 0, 0);
    }
    __builtin_amdgcn_s_setprio(0);
  }

  // epilogue: denom D[0][q] lives in lane q (quad 0), reg 0; broadcast via shfl
  #pragma unroll
  for (int qt = 0; qt < 2; qt++){
    float ls = __shfl(lacc[qt][0], l15);
    float inv = 1.0f / ls;
    size_t row = rowbase + n0 + wave * 32 + qt * 16 + l15;
    #pragma unroll
    for (int dt = 0; dt < 4; dt++){
      int col = h * HD + dt * 16 + quad * 4;
      unsigned p0 = (unsigned short)f2bf(o[dt][qt][0] * inv) |
                    ((unsigned)(unsigned short)f2bf(o[dt][qt][1] * inv) << 16);
      unsigned p1 = (unsigned short)f2bf(o[dt][qt][2] * inv) |
                    ((unsigned)(unsigned short)f2bf(o[dt][qt][3] * inv) << 16);
      *(unsigned*)(Y + row * DV + col)     = p0;
      *(unsigned*)(Y + row * DV + col + 2) = p1;
    }
  }
}

extern "C" void kernel_launch(void* const* d_in, const int* in_sizes, int n_in,
                              void* d_out, int out_size, void* d_ws, size_t ws_size,
                              hipStream_t stream) {
  const float* kv = (const float*)d_in[0];
  const float* q  = (const float*)d_in[1];
  const float* Wk = (const float*)d_in[2];
  const float* bk = (const float*)d_in[3];
  const float* Wq = (const float*)d_in[4];
  const float* bq = (const float*)d_in[5];
  const float* Wv = (const float*)d_in[6];
  const float* bv = (const float*)d_in[7];
  const float* Wp = (const float*)d_in[8];
  const float* bp = (const float*)d_in[9];

  const size_t E  = 4194304;  // 4096*1024
  const size_t WE = 1048576;  // 1024*1024
  short* p   = (short*)d_ws;
  short* kvb = p; p += E;
  short* qb  = p; p += E;
  short* Wkt = p; p += WE;
  short* Wqt = p; p += WE;
  short* Wvt = p; p += WE;
  short* Wpt = p; p += WE;
  short* Kp  = p; p += E;
  short* Qp  = p; p += E;
  short* VT  = p; p += E;
  short* Yb  = p; p += E;

  cvt2<<<dim3(512, 2), 256, 0, stream>>>(kv, q, kvb, qb, (int)E);
  tcvt4<<<dim3(16, 16, 4), 256, 0, stream>>>(Wk, Wq, Wv, Wp, Wkt, Wqt, Wvt, Wpt);

  // Qp = (q@Wq+bq)*0.125*log2e ; Kp = kv@Wk+bk ; VT = (kv@Wv+bv)^T
  projP<<<512, 256, 0, stream>>>(qb, kvb, Wqt, Wkt, Wvt, bq, bk, bv,
                                 Qp, Kp, VT, 0.18033688011f);

  attn<<<512, 256, 0, stream>>>(Qp, Kp, VT, Yb);

  // out = Y@Wp + bp  (f32 output)
  gemm_f32<<<512, 256, 0, stream>>>(Yb, Wpt, bp, (float*)d_out);
}

// Round 12
// 197.470 us; speedup vs baseline: 1.0034x; 1.0034x over previous
//
#include <hip/hip_runtime.h>

#define DV 1024
#define HD 64

typedef short v4s __attribute__((ext_vector_type(4)));
typedef short v8s __attribute__((ext_vector_type(8)));
typedef float v4f __attribute__((ext_vector_type(4)));
typedef int   v2i __attribute__((ext_vector_type(2)));

__device__ __forceinline__ short f2bf(float x){
  unsigned u = __float_as_uint(x);
  u += 0x7FFFu + ((u >> 16) & 1u);
  return (short)(u >> 16);
}

// XOR-swizzle for 64-short rows read as b128 (8-lane phases → conflict-free)
__device__ __forceinline__ int swz(int lane){
  return (((lane & 7) ^ (lane >> 3)) << 3);   // in shorts
}

// async global->LDS, 16B per lane; LDS dest is wave-uniform base + lane*16
__device__ __forceinline__ void gload16(const short* g, short* l){
  __builtin_amdgcn_global_load_lds(
      (const __attribute__((address_space(1))) void*)g,
      (__attribute__((address_space(3))) void*)l,
      16, 0, 0);
}

// ---------- f32 -> bf16 convert, 2 tensors in one launch ----------
__global__ __launch_bounds__(256) void cvt2(const float* __restrict__ xa,
                                            const float* __restrict__ xb,
                                            short* __restrict__ ya,
                                            short* __restrict__ yb, int n){
  const float* x = blockIdx.y ? xb : xa;
  short* y = blockIdx.y ? yb : ya;
  int stride = gridDim.x * 256 * 4;
  for (int i = (blockIdx.x * 256 + threadIdx.x) * 4; i < n; i += stride){
    float4 v = *(const float4*)(x + i);
    v4s s; s.x = f2bf(v.x); s.y = f2bf(v.y); s.z = f2bf(v.z); s.w = f2bf(v.w);
    *(v4s*)(y + i) = s;
  }
}

// ---------- W[k][n] f32 -> Wt[n][k] bf16, all 4 weights in one launch ----------
__global__ __launch_bounds__(256) void tcvt4(
    const float* __restrict__ W0, const float* __restrict__ W1,
    const float* __restrict__ W2, const float* __restrict__ W3,
    short* __restrict__ T0, short* __restrict__ T1,
    short* __restrict__ T2, short* __restrict__ T3){
  const float* W; short* Wt;
  switch (blockIdx.z){
    case 0: W = W0; Wt = T0; break;
    case 1: W = W1; Wt = T1; break;
    case 2: W = W2; Wt = T2; break;
    default: W = W3; Wt = T3; break;
  }
  __shared__ short L[64 * 68];
  const int t = threadIdx.x;
  const int k0 = blockIdx.y * 64, n0 = blockIdx.x * 64;
  const int rr = t >> 4, cc = (t & 15) * 4;
  #pragma unroll
  for (int j = 0; j < 4; j++){
    int r = rr + j * 16;
    float4 v = *(const float4*)(W + (size_t)(k0 + r) * DV + n0 + cc);
    v4s s; s.x = f2bf(v.x); s.y = f2bf(v.y); s.z = f2bf(v.z); s.w = f2bf(v.w);
    *(v4s*)&L[r * 68 + cc] = s;
  }
  __syncthreads();
  #pragma unroll
  for (int j = 0; j < 4; j++){
    int n = rr + j * 16;
    v4s s;
    s.x = L[(cc + 0) * 68 + n];
    s.y = L[(cc + 1) * 68 + n];
    s.z = L[(cc + 2) * 68 + n];
    s.w = L[(cc + 3) * 68 + n];
    *(v4s*)(Wt + (size_t)(n0 + n) * DV + k0 + cc) = s;
  }
}

// ---------- fused projections, PAIRED K/V blocks ----------
__global__ __launch_bounds__(256, 2) void projP(
    const short* __restrict__ qb, const short* __restrict__ kvb,
    const short* __restrict__ Wqt, const short* __restrict__ Wkt,
    const short* __restrict__ Wvt,
    const float* __restrict__ bq, const float* __restrict__ bk,
    const float* __restrict__ bv,
    short* __restrict__ Qp, short* __restrict__ Kp, short* __restrict__ VT,
    float qscale)
{
  __shared__ short S[3 * 8192];   // 48 KB
  const int tid = threadIdx.x;
  const int wave = tid >> 6, lane = tid & 63;
  const int quad = lane >> 4, l15 = lane & 15;
  const int wr = (wave >> 1) * 64, wc = (wave & 1) * 64;
  const int srow = lane >> 3;
  const int sw = swz(lane);
  const int K = 1024;
  const int bid = blockIdx.x;
  const v4f vzero = {0.f, 0.f, 0.f, 0.f};

  if (bid < 256){
    // ---------------- Qp single tile ----------------
    const int m0 = (bid & 31) * 128, n0 = (bid >> 5) * 128;
    short* As = S;
    short* Bs = S + 8192;
    const short* pa[4]; const short* pb[4];
    #pragma unroll
    for (int ii = 0; ii < 4; ii++){
      int i = wave * 4 + ii;
      pa[ii] = qb  + (size_t)(m0 + i * 8 + srow) * K + sw;
      pb[ii] = Wqt + (size_t)(n0 + i * 8 + srow) * K + sw;
    }
    v4f acc[4][4];
    #pragma unroll
    for (int i = 0; i < 4; i++)
      #pragma unroll
      for (int j = 0; j < 4; j++)
        acc[i][j] = vzero;

    for (int kt = 0; kt < K; kt += 64){
      __syncthreads();
      #pragma unroll
      for (int ii = 0; ii < 4; ii++){
        gload16(pa[ii] + kt, &As[(wave * 4 + ii) * 512]);
        gload16(pb[ii] + kt, &Bs[(wave * 4 + ii) * 512]);
      }
      __syncthreads();
      #pragma unroll
      for (int ks = 0; ks < 2; ks++){
        v8s a[4], b[4];
        #pragma unroll
        for (int mt = 0; mt < 4; mt++)
          a[mt] = *(const v8s*)&As[(wr + mt * 16 + l15) * 64 + (((ks * 4 + quad) ^ (l15 & 7)) << 3)];
        #pragma unroll
        for (int nt = 0; nt < 4; nt++)
          b[nt] = *(const v8s*)&Bs[(wc + nt * 16 + l15) * 64 + (((ks * 4 + quad) ^ (l15 & 7)) << 3)];
        #pragma unroll
        for (int mt = 0; mt < 4; mt++)
          #pragma unroll
          for (int nt = 0; nt < 4; nt++)
            acc[mt][nt] = __builtin_amdgcn_mfma_f32_16x16x32_bf16(a[mt], b[nt], acc[mt][nt], 0, 0, 0);
      }
    }
    #pragma unroll
    for (int mt = 0; mt < 4; mt++){
      #pragma unroll
      for (int nt = 0; nt < 4; nt++){
        int row = m0 + wr + mt * 16 + quad * 4;
        int col = n0 + wc + nt * 16 + l15;
        float bcol = bq[col];
        #pragma unroll
        for (int r = 0; r < 4; r++)
          Qp[(size_t)(row + r) * 1024 + col] = f2bf((acc[mt][nt][r] + bcol) * qscale);
      }
    }
  } else {
    // ---------------- paired Kp / VT tiles ----------------
    const int l = bid - 256;
    const int m0 = (l & 31) * 128;        // kv-row tile (32)
    const int j0 = (l >> 5) * 128;        // Kp col-tile == VT row-tile (8)
    short* kvS = S;
    short* wkS = S + 8192;
    short* wvS = S + 16384;
    const short* pkv[4]; const short* pwk[4]; const short* pwv[4];
    #pragma unroll
    for (int ii = 0; ii < 4; ii++){
      int i = wave * 4 + ii;
      pkv[ii] = kvb + (size_t)(m0 + i * 8 + srow) * K + sw;
      pwk[ii] = Wkt + (size_t)(j0 + i * 8 + srow) * K + sw;
      pwv[ii] = Wvt + (size_t)(j0 + i * 8 + srow) * K + sw;
    }
    v4f acc1[4][4], acc2[4][4];
    #pragma unroll
    for (int i = 0; i < 4; i++)
      #pragma unroll
      for (int j = 0; j < 4; j++){
        acc1[i][j] = vzero; acc2[i][j] = vzero;
      }

    for (int kt = 0; kt < K; kt += 64){
      __syncthreads();
      #pragma unroll
      for (int ii = 0; ii < 4; ii++){
        gload16(pkv[ii] + kt, &kvS[(wave * 4 + ii) * 512]);
        gload16(pwk[ii] + kt, &wkS[(wave * 4 + ii) * 512]);
        gload16(pwv[ii] + kt, &wvS[(wave * 4 + ii) * 512]);
      }
      __syncthreads();
      #pragma unroll
      for (int ks = 0; ks < 2; ks++){
        const int off = ((ks * 4 + quad) ^ (l15 & 7)) << 3;
        v8s a1[4], b1[4], a2[4], b2[4];
        #pragma unroll
        for (int mt = 0; mt < 4; mt++){
          a1[mt] = *(const v8s*)&kvS[(wr + mt * 16 + l15) * 64 + off];
          a2[mt] = *(const v8s*)&wvS[(wr + mt * 16 + l15) * 64 + off];
        }
        #pragma unroll
        for (int nt = 0; nt < 4; nt++){
          b1[nt] = *(const v8s*)&wkS[(wc + nt * 16 + l15) * 64 + off];
          b2[nt] = *(const v8s*)&kvS[(wc + nt * 16 + l15) * 64 + off];
        }
        #pragma unroll
        for (int mt = 0; mt < 4; mt++)
          #pragma unroll
          for (int nt = 0; nt < 4; nt++){
            acc1[mt][nt] = __builtin_amdgcn_mfma_f32_16x16x32_bf16(a1[mt], b1[nt], acc1[mt][nt], 0, 0, 0);
            acc2[mt][nt] = __builtin_amdgcn_mfma_f32_16x16x32_bf16(a2[mt], b2[nt], acc2[mt][nt], 0, 0, 0);
          }
      }
    }
    // Kp epilogue: row = kv-m, col = j0-dim, bias per col
    #pragma unroll
    for (int mt = 0; mt < 4; mt++){
      #pragma unroll
      for (int nt = 0; nt < 4; nt++){
        int row = m0 + wr + mt * 16 + quad * 4;
        int col = j0 + wc + nt * 16 + l15;
        float bcol = bk[col];
        #pragma unroll
        for (int r = 0; r < 4; r++)
          Kp[(size_t)(row + r) * 1024 + col] = f2bf(acc1[mt][nt][r] + bcol);
      }
    }
    // VT epilogue: row = d (j0), col = kv-m, bias per row
    #pragma unroll
    for (int mt = 0; mt < 4; mt++){
      #pragma unroll
      for (int nt = 0; nt < 4; nt++){
        int row = j0 + wr + mt * 16 + quad * 4;
        int col = m0 + wc + nt * 16 + l15;
        #pragma unroll
        for (int r = 0; r < 4; r++)
          VT[(size_t)(row + r) * 4096 + col] = f2bf(acc2[mt][nt][r] + bv[row + r]);
      }
    }
  }
}

// ---------- final GEMM: 128x64 tiles, register-prefetch ----------
__global__ __launch_bounds__(256, 2) void gemm_f32(
    const short* __restrict__ A, const short* __restrict__ Bt,
    const float* __restrict__ bias, float* __restrict__ C)
{
  __shared__ short As[128 * 64];
  __shared__ short Bs[64 * 64];
  const int tid = threadIdx.x;
  const int wave = tid >> 6, lane = tid & 63;
  const int quad = lane >> 4, l15 = lane & 15;
  const int bid = blockIdx.x;
  const int m0 = (bid & 31) * 128, n0 = (bid >> 5) * 64;
  const int wr = (wave >> 1) * 64, wc = (wave & 1) * 32;
  const int srow = lane >> 3;
  const int sw = swz(lane);
  const int K = 1024;
  const v4f vzero = {0.f, 0.f, 0.f, 0.f};

  const short* pa[4]; const short* pb[2];
  #pragma unroll
  for (int ii = 0; ii < 4; ii++)
    pa[ii] = A + (size_t)(m0 + (wave * 4 + ii) * 8 + srow) * K + sw;
  #pragma unroll
  for (int ii = 0; ii < 2; ii++)
    pb[ii] = Bt + (size_t)(n0 + (wave * 2 + ii) * 8 + srow) * K + sw;

  v8s ra[4], rb[2];
  #pragma unroll
  for (int ii = 0; ii < 4; ii++) ra[ii] = *(const v8s*)(pa[ii]);
  #pragma unroll
  for (int ii = 0; ii < 2; ii++) rb[ii] = *(const v8s*)(pb[ii]);

  v4f acc[4][2];
  #pragma unroll
  for (int i = 0; i < 4; i++){ acc[i][0] = vzero; acc[i][1] = vzero; }

  for (int kt = 0; kt < K; kt += 64){
    __syncthreads();
    #pragma unroll
    for (int ii = 0; ii < 4; ii++)
      *(v8s*)&As[(wave * 4 + ii) * 512 + lane * 8] = ra[ii];
    #pragma unroll
    for (int ii = 0; ii < 2; ii++)
      *(v8s*)&Bs[(wave * 2 + ii) * 512 + lane * 8] = rb[ii];
    __syncthreads();
    if (kt + 64 < K){
      #pragma unroll
      for (int ii = 0; ii < 4; ii++) ra[ii] = *(const v8s*)(pa[ii] + kt + 64);
      #pragma unroll
      for (int ii = 0; ii < 2; ii++) rb[ii] = *(const v8s*)(pb[ii] + kt + 64);
    }
    #pragma unroll
    for (int ks = 0; ks < 2; ks++){
      v8s a[4], b[2];
      #pragma unroll
      for (int mt = 0; mt < 4; mt++)
        a[mt] = *(const v8s*)&As[(wr + mt * 16 + l15) * 64 + (((ks * 4 + quad) ^ (l15 & 7)) << 3)];
      #pragma unroll
      for (int nt = 0; nt < 2; nt++)
        b[nt] = *(const v8s*)&Bs[(wc + nt * 16 + l15) * 64 + (((ks * 4 + quad) ^ (l15 & 7)) << 3)];
      #pragma unroll
      for (int mt = 0; mt < 4; mt++)
        #pragma unroll
        for (int nt = 0; nt < 2; nt++)
          acc[mt][nt] = __builtin_amdgcn_mfma_f32_16x16x32_bf16(a[mt], b[nt], acc[mt][nt], 0, 0, 0);
    }
  }

  #pragma unroll
  for (int mt = 0; mt < 4; mt++){
    #pragma unroll
    for (int nt = 0; nt < 2; nt++){
      int row = m0 + wr + mt * 16 + quad * 4;
      int col = n0 + wc + nt * 16 + l15;
      float bcol = bias[col];
      #pragma unroll
      for (int r = 0; r < 4; r++)
        C[(size_t)(row + r) * 1024 + col] = acc[mt][nt][r] + bcol;
    }
  }
}

// ---------- flash attention v9 (round-9 measured best, setprio removed):
// x32 PV, P via XOR-64 per-wave LDS tile, V stride 72, MFMA softmax denom ----------
__global__ __launch_bounds__(256, 3) void attn(
    const short* __restrict__ Qp, const short* __restrict__ Kp,
    const short* __restrict__ Vt, short* __restrict__ Y)
{
  __shared__ short Ks[64 * 64];
  __shared__ short Vs[64 * 72];
  __shared__ short Ps[4 * 2048];   // per-wave P tiles: [wave][qt][q=16][kv=64 swz]
  const int tid = threadIdx.x;
  const int wave = tid >> 6, lane = tid & 63;
  const int quad = lane >> 4, l15 = lane & 15;
  const int gid = blockIdx.x;
  const int qi = gid >> 5, bh = gid & 31;   // gid%8 == h%8 -> (b,h) pinned to XCD
  const int h = bh & 15, b = bh >> 4;
  const int n0 = qi * 128;
  const int srow = lane >> 3;
  const int c8 = (lane & 7) * 8;
  const int sw = swz(lane);
  const size_t rowbase = (size_t)b * 2048;
  const v4f vzero = {0.f, 0.f, 0.f, 0.f};
  const int l7 = l15 & 7;
  short* Pw = Ps + wave * 2048;

  // ones-row A fragment for 16x16x32: A[row][k]=(row==0); row=l15, k=quad*8+j
  const short oo = (l15 == 0) ? (short)0x3F80 : (short)0;
  const v8s aones8 = {oo, oo, oo, oo, oo, oo, oo, oo};

  v8s qf[2][2];
  #pragma unroll
  for (int qt = 0; qt < 2; qt++){
    const short* qrow = Qp + (rowbase + n0 + wave * 32 + qt * 16 + l15) * DV + h * HD + quad * 8;
    qf[qt][0] = *(const v8s*)(qrow);
    qf[qt][1] = *(const v8s*)(qrow + 32);
  }

  const short* pk[2]; const short* pv[2];
  #pragma unroll
  for (int ii = 0; ii < 2; ii++){
    int i = wave * 2 + ii;
    pk[ii] = Kp + (rowbase + i * 8 + srow) * DV + h * HD + sw;
    pv[ii] = Vt + (size_t)(h * HD + i * 8 + srow) * 4096 + rowbase + c8;
  }
  v8s rk[2], rv[2];
  #pragma unroll
  for (int ii = 0; ii < 2; ii++){ rk[ii] = *(const v8s*)(pk[ii]); rv[ii] = *(const v8s*)(pv[ii]); }

  v4f o[4][2];
  #pragma unroll
  for (int dt = 0; dt < 4; dt++){ o[dt][0] = vzero; o[dt][1] = vzero; }
  v4f lacc[2];
  lacc[0] = vzero; lacc[1] = vzero;

  for (int kt = 0; kt < 32; kt++){
    __syncthreads();
    #pragma unroll
    for (int ii = 0; ii < 2; ii++){
      int i = wave * 2 + ii;
      *(v8s*)&Ks[i * 512 + lane * 8] = rk[ii];
      *(v8s*)&Vs[(i * 8 + srow) * 72 + c8] = rv[ii];
    }
    __syncthreads();
    if (kt < 31){
      #pragma unroll
      for (int ii = 0; ii < 2; ii++){
        rk[ii] = *(const v8s*)(pk[ii] + (size_t)(kt + 1) * 64 * DV);
        rv[ii] = *(const v8s*)(pv[ii] + (kt + 1) * 64);
      }
    }

    // S^T = K * Q^T via 16x16x32: s[qt][kvt] reg r -> (kv = kvt*16+quad*4+r, q = l15)
    v4f s[2][4];
    #pragma unroll
    for (int qt = 0; qt < 2; qt++)
      #pragma unroll
      for (int kvt = 0; kvt < 4; kvt++) s[qt][kvt] = vzero;
    #pragma unroll
    for (int ks = 0; ks < 2; ks++){
      v8s a[4];
      #pragma unroll
      for (int kvt = 0; kvt < 4; kvt++)
        a[kvt] = *(const v8s*)&Ks[(kvt * 16 + l15) * 64 + (((ks * 4 + quad) ^ l7) << 3)];
      #pragma unroll
      for (int kvt = 0; kvt < 4; kvt++)
        #pragma unroll
        for (int qt = 0; qt < 2; qt++)
          s[qt][kvt] = __builtin_amdgcn_mfma_f32_16x16x32_bf16(a[kvt], qf[qt][ks], s[qt][kvt], 0, 0, 0);
    }

    // p = exp2(s); pack to bf16 and write into per-wave P tile (swizzled):
    // logical layout P[q=l15][kv], group g=kv>>3 stored at (g^l7)*8.
    #pragma unroll
    for (int qt = 0; qt < 2; qt++)
      #pragma unroll
      for (int kvt = 0; kvt < 4; kvt++){
        float p0 = __builtin_amdgcn_exp2f(s[qt][kvt][0]);
        float p1 = __builtin_amdgcn_exp2f(s[qt][kvt][1]);
        float p2 = __builtin_amdgcn_exp2f(s[qt][kvt][2]);
        float p3 = __builtin_amdgcn_exp2f(s[qt][kvt][3]);
        unsigned u0 = __float_as_uint(p0) + 0x8000u;
        unsigned u1 = __float_as_uint(p1) + 0x8000u;
        unsigned u2 = __float_as_uint(p2) + 0x8000u;
        unsigned u3 = __float_as_uint(p3) + 0x8000u;
        v2i pi;
        pi.x = (int)__builtin_amdgcn_perm(u1, u0, 0x07060302u);
        pi.y = (int)__builtin_amdgcn_perm(u3, u2, 0x07060302u);
        // kv = kvt*16 + quad*4 + r -> group g = kvt*2 + (quad>>1), sub = (quad&1)*4
        *(v4s*)&Pw[qt * 1024 + l15 * 64 +
                   ((((kvt << 1) | (quad >> 1)) ^ l7) << 3) + ((quad & 1) << 2)]
            = __builtin_bit_cast(v4s, pi);
      }

    // O^T += V^T * P^T on x32 shape: A = V^T (k=kv=blk*32+quad*8+j),
    // B = P (col=q=l15, same k); denominator via ones-row A.
    #pragma unroll
    for (int blk = 0; blk < 2; blk++){
      v8s av[4], pb[2];
      #pragma unroll
      for (int qt = 0; qt < 2; qt++)
        pb[qt] = *(const v8s*)&Pw[qt * 1024 + l15 * 64 + ((((blk << 2) | quad) ^ l7) << 3)];
      #pragma unroll
      for (int dt = 0; dt < 4; dt++)
        av[dt] = *(const v8s*)&Vs[(dt * 16 + l15) * 72 + blk * 32 + quad * 8];
      #pragma unroll
      for (int dt = 0; dt < 4; dt++)
        #pragma unroll
        for (int qt = 0; qt < 2; qt++)
          o[dt][qt] = __builtin_amdgcn_mfma_f32_16x16x32_bf16(av[dt], pb[qt], o[dt][qt], 0, 0, 0);
      #pragma unroll
      for (int qt = 0; qt < 2; qt++)
        lacc[qt] = __builtin_amdgcn_mfma_f32_16x16x32_bf16(aones8, pb[qt], lacc[qt], 0, 0, 0);
    }
  }

  // epilogue: denom D[0][q] lives in lane q (quad 0), reg 0; broadcast via shfl
  #pragma unroll
  for (int qt = 0; qt < 2; qt++){
    float ls = __shfl(lacc[qt][0], l15);
    float inv = 1.0f / ls;
    size_t row = rowbase + n0 + wave * 32 + qt * 16 + l15;
    #pragma unroll
    for (int dt = 0; dt < 4; dt++){
      int col = h * HD + dt * 16 + quad * 4;
      unsigned p0 = (unsigned short)f2bf(o[dt][qt][0] * inv) |
                    ((unsigned)(unsigned short)f2bf(o[dt][qt][1] * inv) << 16);
      unsigned p1 = (unsigned short)f2bf(o[dt][qt][2] * inv) |
                    ((unsigned)(unsigned short)f2bf(o[dt][qt][3] * inv) << 16);
      *(unsigned*)(Y + row * DV + col)     = p0;
      *(unsigned*)(Y + row * DV + col + 2) = p1;
    }
  }
}

extern "C" void kernel_launch(void* const* d_in, const int* in_sizes, int n_in,
                              void* d_out, int out_size, void* d_ws, size_t ws_size,
                              hipStream_t stream) {
  const float* kv = (const float*)d_in[0];
  const float* q  = (const float*)d_in[1];
  const float* Wk = (const float*)d_in[2];
  const float* bk = (const float*)d_in[3];
  const float* Wq = (const float*)d_in[4];
  const float* bq = (const float*)d_in[5];
  const float* Wv = (const float*)d_in[6];
  const float* bv = (const float*)d_in[7];
  const float* Wp = (const float*)d_in[8];
  const float* bp = (const float*)d_in[9];

  const size_t E  = 4194304;  // 4096*1024
  const size_t WE = 1048576;  // 1024*1024
  short* p   = (short*)d_ws;
  short* kvb = p; p += E;
  short* qb  = p; p += E;
  short* Wkt = p; p += WE;
  short* Wqt = p; p += WE;
  short* Wvt = p; p += WE;
  short* Wpt = p; p += WE;
  short* Kp  = p; p += E;
  short* Qp  = p; p += E;
  short* VT  = p; p += E;
  short* Yb  = p; p += E;

  cvt2<<<dim3(512, 2), 256, 0, stream>>>(kv, q, kvb, qb, (int)E);
  tcvt4<<<dim3(16, 16, 4), 256, 0, stream>>>(Wk, Wq, Wv, Wp, Wkt, Wqt, Wvt, Wpt);

  // Qp = (q@Wq+bq)*0.125*log2e ; Kp = kv@Wk+bk ; VT = (kv@Wv+bv)^T
  projP<<<512, 256, 0, stream>>>(qb, kvb, Wqt, Wkt, Wvt, bq, bk, bv,
                                 Qp, Kp, VT, 0.18033688011f);

  attn<<<512, 256, 0, stream>>>(Qp, Kp, VT, Yb);

  // out = Y@Wp + bp  (f32 output)
  gemm_f32<<<512, 256, 0, stream>>>(Yb, Wpt, bp, (float*)d_out);
}